// Round 7
// baseline (1095.722 us; speedup 1.0000x reference)
//
#include <hip/hip_runtime.h>
#include <hip/hip_bf16.h>
#include <hip/hip_cooperative_groups.h>

namespace cg = cooperative_groups;

// Sparse 3^3 conv x2 + LayerNorm + ReLU + residual. N=400000, C=32, K=27.
// Contract: ALL float inputs are FLOAT32, output f32, nbr int32.
// Workspace: h (bf16, 25.6MB) at d_ws+0; xb (bf16 copy of x) at +25.6MB.
//
// Round-7 (post-mortem r6: DEADLOCK, derivable from r5 counters. r5 compiled
// to 128 arch VGPR + 64 AGPR ~= 192 regs/wave -> 2 waves/SIMD -> 1 block/CU;
// the occupancy API's bpc=1 was CORRECT, not conservative. r6 hardcoded 512
// coop blocks under the same (512,2) bound -> only ~256 co-resident ->
// grid.sync() hang at graph replay. Fix: __launch_bounds__(512,4) caps total
// regs at 128/wave -> 4 waves/SIMD -> 2 blocks/CU SCHEDULABLE BY THE BOUND
// -> 512 coop blocks always fit; deadlock class eliminated. Spill risk is
// low: the merged runtime-wout conv_pass body is the r2-proven loop (60 arch
// VGPR + 32 acc AGPR ~= 96 total under this exact bound, zero spill); r4's
// spill came from TWO inlined template instantiations, not the body size.
// Pre-committed decision rule: WRITE>150MB or error -> abandon fusion.)

#define NV   400000
#define NT   782        // ceil(NV / 512) tiles of 512 voxels
#define NBLK 512        // persistent blocks: 2/CU guaranteed by (512,4) bound

typedef __bf16 bf16x8 __attribute__((ext_vector_type(8)));
typedef float  f32x4  __attribute__((ext_vector_type(4)));

union ABu { bf16x8 v; int4 i4; unsigned short us[8]; };

__device__ __forceinline__ unsigned short rb_f2bf(float f) {
    unsigned int u = __float_as_uint(f);
    return (unsigned short)((u + 0x7fffu + ((u >> 16) & 1u)) >> 16);
}

// k index for the 26 non-center offsets (skips k=13, the identity offset)
#define KIDX(kk) ((kk) + ((kk) >= 13 ? 1 : 0))

#define MFMA_BF16 __builtin_amdgcn_mfma_f32_16x16x32_bf16

// ---- shared building blocks -------------------------------------------------

// Fill LDS B-table for the 26 non-center offsets from f32 weights.
// Bp[kk*1024 + f*512 + lane*8 + j] = W[k][ci=(lane>>4)*8+j][co=(lane&15)+16f]
__device__ __forceinline__ void fill_btable(unsigned short* Bp,
                                            const float* __restrict__ Wf)
{
    for (int e = threadIdx.x; e < 26 * 1024; e += 512) {
        int kk = e >> 10;
        int k  = KIDX(kk);
        int r  = e & 1023;
        int f  = r >> 9;
        int ll = (r >> 3) & 63;
        int j  = r & 7;
        int ci = ((ll >> 4) << 3) + j;
        int co = (ll & 15) + (f << 4);
        Bp[e] = rb_f2bf(Wf[k * 1024 + ci * 32 + co]);
    }
}

// Gather the 4 tile-slots for one offset from a wave-wide index register.
// jall lane l holds nbr index of voxel i0+l; tile t row n needs lane t*16+n.
#define GATHER4(gbuf, jall)                                                   \
    do {                                                                      \
        _Pragma("unroll")                                                     \
        for (int _t = 0; _t < 4; ++_t) {                                      \
            int _j = __shfl((jall), _t * 16 + n);                             \
            gbuf[_t] = make_int4(0, 0, 0, 0);                                 \
            if (_j >= 0)                                                      \
                gbuf[_t] = *(const int4*)(gsrc + ((size_t)_j << 5) + qo);     \
        }                                                                     \
    } while (0)

// Consume one offset's gather buffer: 2 LDS B-frag reads + 8 MFMAs.
#define CONSUME(kk, gbuf)                                                     \
    do {                                                                      \
        ABu _b0, _b1;                                                         \
        _b0.i4 = *(const int4*)(Bp + (kk) * 1024 + lane * 8);                 \
        _b1.i4 = *(const int4*)(Bp + (kk) * 1024 + 512 + lane * 8);           \
        _Pragma("unroll")                                                     \
        for (int _t = 0; _t < 4; ++_t) {                                      \
            ABu _a; _a.i4 = gbuf[_t];                                         \
            acc[_t][0] = MFMA_BF16(_a.v, _b0.v, acc[_t][0], 0, 0, 0);         \
            acc[_t][1] = MFMA_BF16(_a.v, _b1.v, acc[_t][1], 0, 0, 0);         \
        }                                                                     \
    } while (0)

#define NBLOAD(kk)                                                            \
    (okv ? __builtin_nontemporal_load(nbr + (size_t)KIDX(kk) * NV + v64) : -1)

// One conv+LN pass over tiles [start, NT) step stride. r2-proven inner loop:
// 64 vox/wave, named gA/gB double-buffered gathers, 2-pair index prefetch.
// wout=false: h(bf16) = relu(LN(conv(gsrc)))
// wout=true : out(f32) = relu(LN(conv(gsrc)) + x)
__device__ __forceinline__ void conv_pass(
    bool wout, int start, int stride,
    const unsigned short* Bp,          // LDS B-table (filled + synced)
    const float* __restrict__ Wf,      // weights (for center k=13 frags)
    const float* __restrict__ xf,      // residual source (pass 2)
    const int*   __restrict__ nbr,
    const float* __restrict__ gf,
    const float* __restrict__ bfv,
    float*       __restrict__ outf,
    unsigned short* __restrict__ hbuf,
    const unsigned short* __restrict__ gsrc)
{
    const int lane = threadIdx.x & 63;
    const int wv   = threadIdx.x >> 6;
    const int q    = lane >> 4, n = lane & 15;
    const int qo   = q * 8;
    const float gv0 = gf[n],  gv1 = gf[n + 16];
    const float bv0 = bfv[n], bv1 = bfv[n + 16];

    // center-offset (k=13, identity map) B fragments -> registers
    ABu cb0, cb1;
    #pragma unroll
    for (int j = 0; j < 8; ++j) {
        int ci = (q << 3) + j;
        cb0.us[j] = rb_f2bf(Wf[13 * 1024 + ci * 32 + n]);
        cb1.us[j] = rb_f2bf(Wf[13 * 1024 + ci * 32 + n + 16]);
    }

    for (int tile = start; tile < NT; tile += stride) {
        const int  i0  = tile * 512 + wv * 64;     // 64 voxels per wave
        const int  v64 = i0 + lane;
        const bool okv = v64 < NV;

        f32x4 acc[4][2];
        #pragma unroll
        for (int t = 0; t < 4; ++t) {
            acc[t][0] = (f32x4){0.f, 0.f, 0.f, 0.f};
            acc[t][1] = (f32x4){0.f, 0.f, 0.f, 0.f};
        }

        // prologue: indices kk=0,1; center self-rows; gathers kk=0,1; idx 2,3
        int jA = NBLOAD(0);
        int jB = NBLOAD(1);

        int4 cgb[4];
        #pragma unroll
        for (int t = 0; t < 4; ++t) {
            int vt = i0 + t * 16 + n;
            cgb[t] = make_int4(0, 0, 0, 0);
            if (vt < NV) cgb[t] = *(const int4*)(gsrc + ((size_t)vt << 5) + qo);
        }

        int4 gA[4], gB[4];
        GATHER4(gA, jA);                   // kk=0
        GATHER4(gB, jB);                   // kk=1

        int jE = NBLOAD(2);
        int jO = NBLOAD(3);

        #pragma unroll
        for (int t = 0; t < 4; ++t) {      // center MFMA (frees cgb)
            ABu a; a.i4 = cgb[t];
            acc[t][0] = MFMA_BF16(a.v, cb0.v, acc[t][0], 0, 0, 0);
            acc[t][1] = MFMA_BF16(a.v, cb1.v, acc[t][1], 0, 0, 0);
        }

        // main pipeline: 13 fully-unrolled pairs, all register names static.
        #pragma unroll
        for (int p = 0; p < 13; ++p) {
            int jE2 = -1, jO2 = -1;
            if (2 * p + 4 < 26) jE2 = NBLOAD(2 * p + 4);
            if (2 * p + 5 < 26) jO2 = NBLOAD(2 * p + 5);

            CONSUME(2 * p, gA);
            if (2 * p + 2 < 26) GATHER4(gA, jE);

            CONSUME(2 * p + 1, gB);
            if (2 * p + 3 < 26) GATHER4(gB, jO);

            jE = jE2; jO = jO2;
        }

        // epilogue. C/D layout: cout = lane&15 (+16 frag1), voxel row = q*4+r.
        #pragma unroll
        for (int t = 0; t < 4; ++t) {
            #pragma unroll
            for (int r = 0; r < 4; ++r) {
                float x0 = acc[t][0][r], x1 = acc[t][1][r];
                float s  = x0 + x1;
                float ss = x0 * x0 + x1 * x1;
                #pragma unroll
                for (int mm = 1; mm <= 8; mm <<= 1) {  // LN reduce, 16-lane group
                    s  += __shfl_xor(s, mm);
                    ss += __shfl_xor(ss, mm);
                }
                float mu  = s * (1.f / 32.f);
                float var = ss * (1.f / 32.f) - mu * mu;
                float rs  = rsqrtf(var + 1e-6f);
                int vv = i0 + t * 16 + q * 4 + r;
                if (vv < NV) {
                    float y0 = (x0 - mu) * rs * gv0 + bv0;
                    float y1 = (x1 - mu) * rs * gv1 + bv1;
                    if (wout) {
                        y0 += xf[(size_t)vv * 32 + n];
                        y1 += xf[(size_t)vv * 32 + n + 16];
                        outf[(size_t)vv * 32 + n]      = fmaxf(y0, 0.f);
                        outf[(size_t)vv * 32 + n + 16] = fmaxf(y1, 0.f);
                    } else {
                        hbuf[(size_t)vv * 32 + n]      = rb_f2bf(fmaxf(y0, 0.f));
                        hbuf[(size_t)vv * 32 + n + 16] = rb_f2bf(fmaxf(y1, 0.f));
                    }
                }
            }
        }
    }
}

// ---- fused persistent cooperative kernel -----------------------------------
// 512 blocks x 512 thr, __launch_bounds__(512,4): total regs capped at
// 128/wave -> 4 waves/SIMD -> 2 blocks/CU schedulable -> 512 coop blocks
// always co-resident (deadlock impossible). Single merged conv_pass body
// (runtime wout) keeps the allocation at the r2-proven ~96 regs.
__global__ __launch_bounds__(512, 4) void ResidualBlock_37452114821416_kernel(
    const float* __restrict__ xf,
    const int*   __restrict__ nbr,
    const float* __restrict__ W1f,
    const float* __restrict__ g1f,
    const float* __restrict__ b1f,
    const float* __restrict__ W2f,
    const float* __restrict__ g2f,
    const float* __restrict__ b2f,
    float*       __restrict__ outf,
    unsigned short* __restrict__ hbuf,
    unsigned short* __restrict__ xb)
{
    __shared__ __align__(16) unsigned short Bp[26 * 1024];
    cg::grid_group grid = cg::this_grid();

    // ---- phase 0: xb = bf16(x), grid-stride over 1.6M 8-float chunks ----
    for (size_t c = (size_t)blockIdx.x * 512 + threadIdx.x;
         c < (size_t)NV * 32 / 8; c += (size_t)NBLK * 512) {
        size_t i = c * 8;
        float4 p0 = *(const float4*)(xf + i);
        float4 p1 = *(const float4*)(xf + i + 4);
        ABu a;
        a.us[0] = rb_f2bf(p0.x); a.us[1] = rb_f2bf(p0.y);
        a.us[2] = rb_f2bf(p0.z); a.us[3] = rb_f2bf(p0.w);
        a.us[4] = rb_f2bf(p1.x); a.us[5] = rb_f2bf(p1.y);
        a.us[6] = rb_f2bf(p1.z); a.us[7] = rb_f2bf(p1.w);
        *(int4*)(xb + i) = a.i4;
    }
    __threadfence();
    grid.sync();

    // ---- phases 1,2: single shared conv body, runtime-selected operands ----
    #pragma unroll 1
    for (int ph = 0; ph < 2; ++ph) {
        const bool  wout = (ph == 1);
        const float* Wf  = wout ? W2f : W1f;
        const float* gfv = wout ? g2f : g1f;
        const float* bfp = wout ? b2f : b1f;
        const unsigned short* gsrc = wout ? hbuf : xb;

        fill_btable(Bp, Wf);
        __syncthreads();
        conv_pass(wout, blockIdx.x, NBLK, Bp, Wf,
                  xf, nbr, gfv, bfp, outf, hbuf, gsrc);
        __threadfence();
        grid.sync();
    }
}

// ---- fallback wrappers (r2-equivalent 3-kernel path, (512,4) = r2 profile) --

__global__ __launch_bounds__(512) void xcvt_kernel(const float* __restrict__ xf,
                                                   unsigned short* __restrict__ xb)
{
    size_t i = ((size_t)blockIdx.x * 512 + threadIdx.x) * 8;
    float4 p0 = *(const float4*)(xf + i);
    float4 p1 = *(const float4*)(xf + i + 4);
    ABu a;
    a.us[0] = rb_f2bf(p0.x); a.us[1] = rb_f2bf(p0.y);
    a.us[2] = rb_f2bf(p0.z); a.us[3] = rb_f2bf(p0.w);
    a.us[4] = rb_f2bf(p1.x); a.us[5] = rb_f2bf(p1.y);
    a.us[6] = rb_f2bf(p1.z); a.us[7] = rb_f2bf(p1.w);
    *(int4*)(xb + i) = a.i4;
}

template <bool WRITE_OUT>
__global__ __launch_bounds__(512, 4) void pass_kernel(
    const float* __restrict__ xf, const int* __restrict__ nbr,
    const float* __restrict__ Wf, const float* __restrict__ gf,
    const float* __restrict__ bfv, float* __restrict__ outf,
    unsigned short* __restrict__ hbuf, const unsigned short* __restrict__ gsrc)
{
    __shared__ __align__(16) unsigned short Bp[26 * 1024];
    fill_btable(Bp, Wf);
    __syncthreads();
    conv_pass(WRITE_OUT, blockIdx.x, gridDim.x, Bp, Wf,
              xf, nbr, gf, bfv, outf, hbuf, gsrc);
}

// Fallback pass-1 for tiny workspace (no xb room): f32 gathers from x.
__global__ __launch_bounds__(512, 4) void pass1_f32_kernel(
    const float* __restrict__ xf, const int* __restrict__ nbr,
    const float* __restrict__ Wf, const float* __restrict__ gf,
    const float* __restrict__ bfv, unsigned short* __restrict__ hbuf)
{
    __shared__ __align__(16) unsigned short Bp[27 * 1024];
    for (int e = threadIdx.x; e < 27 * 1024; e += 512) {
        int k = e >> 10, r = e & 1023, f = r >> 9;
        int ll = (r >> 3) & 63, j = r & 7;
        int ci = ((ll >> 4) << 3) + j, co = (ll & 15) + (f << 4);
        Bp[e] = rb_f2bf(Wf[k * 1024 + ci * 32 + co]);
    }
    __syncthreads();
    const int lane = threadIdx.x & 63, wv = threadIdx.x >> 6;
    const int q = lane >> 4, n = lane & 15;
    const int i0 = blockIdx.x * 512 + wv * 64;
    f32x4 acc[4][2];
    #pragma unroll
    for (int t = 0; t < 4; ++t) { acc[t][0] = (f32x4){0,0,0,0}; acc[t][1] = (f32x4){0,0,0,0}; }
    for (int k = 0; k < 27; ++k) {
        ABu b0, b1;
        b0.i4 = *(const int4*)(Bp + k * 1024 + lane * 8);
        b1.i4 = *(const int4*)(Bp + k * 1024 + 512 + lane * 8);
        const int* nb = nbr + (size_t)k * NV;
        #pragma unroll
        for (int t = 0; t < 4; ++t) {
            int v = i0 + t * 16 + n;
            int jn = (v < NV) ? nb[v] : -1;
            if (__ballot(jn >= 0) == 0ull) continue;
            ABu a; a.i4 = make_int4(0, 0, 0, 0);
            if (jn >= 0) {
                const float* src = xf + (size_t)jn * 32 + q * 8;
                float4 p0 = *(const float4*)(src);
                float4 p1 = *(const float4*)(src + 4);
                a.us[0] = rb_f2bf(p0.x); a.us[1] = rb_f2bf(p0.y);
                a.us[2] = rb_f2bf(p0.z); a.us[3] = rb_f2bf(p0.w);
                a.us[4] = rb_f2bf(p1.x); a.us[5] = rb_f2bf(p1.y);
                a.us[6] = rb_f2bf(p1.z); a.us[7] = rb_f2bf(p1.w);
            }
            acc[t][0] = MFMA_BF16(a.v, b0.v, acc[t][0], 0, 0, 0);
            acc[t][1] = MFMA_BF16(a.v, b1.v, acc[t][1], 0, 0, 0);
        }
    }
    const float gv0 = gf[n], gv1 = gf[n + 16];
    const float bv0 = bfv[n], bv1 = bfv[n + 16];
    #pragma unroll
    for (int t = 0; t < 4; ++t) {
        #pragma unroll
        for (int r = 0; r < 4; ++r) {
            float x0 = acc[t][0][r], x1 = acc[t][1][r];
            float s = x0 + x1, ss = x0 * x0 + x1 * x1;
            #pragma unroll
            for (int mm = 1; mm <= 8; mm <<= 1) { s += __shfl_xor(s, mm); ss += __shfl_xor(ss, mm); }
            float mu = s * (1.f / 32.f);
            float var = ss * (1.f / 32.f) - mu * mu;
            float rs = rsqrtf(var + 1e-6f);
            int vv = i0 + t * 16 + q * 4 + r;
            if (vv < NV) {
                float y0 = (x0 - mu) * rs * gv0 + bv0;
                float y1 = (x1 - mu) * rs * gv1 + bv1;
                hbuf[(size_t)vv * 32 + n]      = rb_f2bf(fmaxf(y0, 0.f));
                hbuf[(size_t)vv * 32 + n + 16] = rb_f2bf(fmaxf(y1, 0.f));
            }
        }
    }
}

extern "C" void kernel_launch(void* const* d_in, const int* in_sizes, int n_in,
                              void* d_out, int out_size, void* d_ws, size_t ws_size,
                              hipStream_t stream)
{
    // setup_inputs() dict order: x, nbr, W1, g1, b1, W2, g2, b2 — all f32 except nbr
    const float* x   = (const float*)d_in[0];
    const int*   nbr = (const int*)d_in[1];
    const float* W1  = (const float*)d_in[2];
    const float* g1  = (const float*)d_in[3];
    const float* b1  = (const float*)d_in[4];
    const float* W2  = (const float*)d_in[5];
    const float* g2  = (const float*)d_in[6];
    const float* b2  = (const float*)d_in[7];
    float* out = (float*)d_out;

    unsigned short* h  = (unsigned short*)d_ws;              // 25.6 MB
    unsigned short* xb = h + (size_t)NV * 32;                // +25.6 MB
    const bool have_xb = ws_size >= (size_t)NV * 32 * 2 * 2; // 51.2 MB needed

    if (have_xb) {
        void* kargs[] = {
            (void*)&x, (void*)&nbr, (void*)&W1, (void*)&g1, (void*)&b1,
            (void*)&W2, (void*)&g2, (void*)&b2, (void*)&out, (void*)&h,
            (void*)&xb
        };
        hipError_t ce = hipLaunchCooperativeKernel(
            (const void*)ResidualBlock_37452114821416_kernel,
            dim3(NBLK), dim3(512), kargs, 0, stream);
        if (ce == hipSuccess) {
            (void)in_sizes; (void)n_in; (void)out_size;
            return;
        }
        (void)hipGetLastError();   // clear, fall through to 3-kernel path
        xcvt_kernel<<<3125, 512, 0, stream>>>(x, xb);
        pass_kernel<false><<<NT, 512, 0, stream>>>(x, nbr, W1, g1, b1, out, h, xb);
    } else {
        pass1_f32_kernel<<<NT, 512, 0, stream>>>(x, nbr, W1, g1, b1, h);
    }
    pass_kernel<true><<<NT, 512, 0, stream>>>(x, nbr, W2, g2, b2, out, h, h);

    (void)in_sizes; (void)n_in; (void)out_size;
}

// Round 9
// 330.734 us; speedup vs baseline: 3.3130x; 3.3130x over previous
//
#include <hip/hip_runtime.h>
#include <hip/hip_bf16.h>

// Sparse 3^3 conv x2 + LayerNorm + ReLU + residual. N=400000, C=32, K=27.
// Contract: ALL float inputs are FLOAT32, output f32, nbr int32.
// Workspace: h (bf16, 25.6MB) at d_ws+0. (xb eliminated in r8.)
//
// Round-9 = round-8 RESUBMITTED UNCHANGED. r8's "MI355X container failed
// twice" was an infra/acquisition error (no compile error, no test, no
// counters) -- not a kernel verdict. Changing the kernel would confound the
// next measurement. Audit re-done: all accesses bounds-guarded; pass 2 is
// structurally byte-identical to r2's twice-passed kernel; no cooperative
// launch (deadlock class gone); no graph-hostile host calls.
//
// Design (from r8): fusion abandoned per pre-committed rule (r4-r7). Best
// verified: r2 = 276.9us = 12(xcvt) + 82 + 82 + ~100us dispatch overhead
// (3 kernels). This version removes ONE dispatch: pass 1 gathers f32
// DIRECTLY from x (r2 pipeline shape, 2x float4 per slot, convert at
// consume -- same rb_f2bf rounding as xcvt => bitwise-identical h), pass 2
// unchanged from r2. Reg audit pass1: ~64 buffer + 32 acc + ~12 misc ~= 108
// <= 128 cap of (512,4). All 27 B-frag sets in LDS (55296B, 2 blocks/CU);
// center consumed in two 2-slot chunks before pipeline buffers go live.
// Tripwire: pass1 VGPR=128 + WRITE>>30MB => spill => revert to exact r2.

#define NV 400000
#define NT 782          // ceil(NV / 512) blocks; 8 waves x 64 voxels each

typedef __bf16 bf16x8 __attribute__((ext_vector_type(8)));
typedef float  f32x4  __attribute__((ext_vector_type(4)));

union ABu { bf16x8 v; int4 i4; unsigned short us[8]; };

__device__ __forceinline__ unsigned short rb_f2bf(float f) {
    unsigned int u = __float_as_uint(f);
    return (unsigned short)((u + 0x7fffu + ((u >> 16) & 1u)) >> 16);
}

// k index for the 26 non-center offsets (skips k=13, the identity offset)
#define KIDX(kk) ((kk) + ((kk) >= 13 ? 1 : 0))

#define MFMA_BF16 __builtin_amdgcn_mfma_f32_16x16x32_bf16

// =====================  PASS 1: f32 gathers from x  ==========================
// h(bf16) = relu(LN(conv1(x))). LDS holds all 27 offsets' B-fragments.

// Gather 4 tile-slots of f32 rows (2x float4 each) for one offset.
#define GATHER4F(fb, jall)                                                    \
    do {                                                                      \
        _Pragma("unroll")                                                     \
        for (int _t = 0; _t < 4; ++_t) {                                      \
            int _j = __shfl((jall), _t * 16 + n);                             \
            fb##0[_t] = make_float4(0.f, 0.f, 0.f, 0.f);                      \
            fb##1[_t] = make_float4(0.f, 0.f, 0.f, 0.f);                      \
            if (_j >= 0) {                                                    \
                const float* _s = xf + ((size_t)_j << 5) + qo;                \
                fb##0[_t] = *(const float4*)(_s);                             \
                fb##1[_t] = *(const float4*)(_s + 4);                         \
            }                                                                 \
        }                                                                     \
    } while (0)

// Consume one offset's f32 buffers: LDS B-frags (k=KIDX(kk)) + convert + MFMA.
#define CONSUMEF(kk, fb)                                                      \
    do {                                                                      \
        ABu _b0, _b1;                                                         \
        _b0.i4 = *(const int4*)(Bp + KIDX(kk) * 1024 + lane * 8);             \
        _b1.i4 = *(const int4*)(Bp + KIDX(kk) * 1024 + 512 + lane * 8);       \
        _Pragma("unroll")                                                     \
        for (int _t = 0; _t < 4; ++_t) {                                      \
            ABu _a;                                                           \
            _a.us[0] = rb_f2bf(fb##0[_t].x); _a.us[1] = rb_f2bf(fb##0[_t].y); \
            _a.us[2] = rb_f2bf(fb##0[_t].z); _a.us[3] = rb_f2bf(fb##0[_t].w); \
            _a.us[4] = rb_f2bf(fb##1[_t].x); _a.us[5] = rb_f2bf(fb##1[_t].y); \
            _a.us[6] = rb_f2bf(fb##1[_t].z); _a.us[7] = rb_f2bf(fb##1[_t].w); \
            acc[_t][0] = MFMA_BF16(_a.v, _b0.v, acc[_t][0], 0, 0, 0);         \
            acc[_t][1] = MFMA_BF16(_a.v, _b1.v, acc[_t][1], 0, 0, 0);         \
        }                                                                     \
    } while (0)

__global__ __launch_bounds__(512, 4) void pass1_kernel(
    const float* __restrict__ xf,     // x [NV,32] f32
    const int*   __restrict__ nbr,    // [27,NV]
    const float* __restrict__ Wf,     // W1 [27,32,32] f32
    const float* __restrict__ gf,     // [32]
    const float* __restrict__ bfv,    // [32]
    unsigned short* __restrict__ hbuf)// [NV,32] bf16 out
{
    // Bp[k*1024 + f*512 + lane*8 + j] = W[k][ci=(lane>>4)*8+j][co=(lane&15)+16f]
    __shared__ __align__(16) unsigned short Bp[27 * 1024];

    const int  lane = threadIdx.x & 63;
    const int  wv   = threadIdx.x >> 6;
    const int  q    = lane >> 4, n = lane & 15;
    const int  i0   = blockIdx.x * 512 + wv * 64;
    const int  v64  = i0 + lane;
    const bool okv  = v64 < NV;
    const int  qo   = q * 8;          // f32-element offset within row

    // index prefetch for the first two pipeline offsets (k=0,1), long latency
    int jA = okv ? __builtin_nontemporal_load(nbr + (size_t)0 * NV + v64) : -1;
    int jB = okv ? __builtin_nontemporal_load(nbr + (size_t)1 * NV + v64) : -1;

    // LDS fill: all 27 offsets
    for (int e = threadIdx.x; e < 27 * 1024; e += 512) {
        int k  = e >> 10;
        int r  = e & 1023;
        int f  = r >> 9;
        int ll = (r >> 3) & 63;
        int j  = r & 7;
        int ci = ((ll >> 4) << 3) + j;
        int co = (ll & 15) + (f << 4);
        Bp[e] = rb_f2bf(Wf[k * 1024 + ci * 32 + co]);
    }
    __syncthreads();

    f32x4 acc[4][2];
    #pragma unroll
    for (int t = 0; t < 4; ++t) {
        acc[t][0] = (f32x4){0.f, 0.f, 0.f, 0.f};
        acc[t][1] = (f32x4){0.f, 0.f, 0.f, 0.f};
    }

    // center (k=13, identity map): 2 slots at a time (16 transient regs),
    // B-frags transient from LDS
    {
        ABu cb0, cb1;
        cb0.i4 = *(const int4*)(Bp + 13 * 1024 + lane * 8);
        cb1.i4 = *(const int4*)(Bp + 13 * 1024 + 512 + lane * 8);
        #pragma unroll
        for (int h2 = 0; h2 < 2; ++h2) {
            float4 c0[2], c1[2];
            #pragma unroll
            for (int tt = 0; tt < 2; ++tt) {
                int vt = i0 + (h2 * 2 + tt) * 16 + n;
                c0[tt] = make_float4(0.f, 0.f, 0.f, 0.f);
                c1[tt] = make_float4(0.f, 0.f, 0.f, 0.f);
                if (vt < NV) {
                    const float* s = xf + ((size_t)vt << 5) + qo;
                    c0[tt] = *(const float4*)(s);
                    c1[tt] = *(const float4*)(s + 4);
                }
            }
            #pragma unroll
            for (int tt = 0; tt < 2; ++tt) {
                ABu a;
                a.us[0] = rb_f2bf(c0[tt].x); a.us[1] = rb_f2bf(c0[tt].y);
                a.us[2] = rb_f2bf(c0[tt].z); a.us[3] = rb_f2bf(c0[tt].w);
                a.us[4] = rb_f2bf(c1[tt].x); a.us[5] = rb_f2bf(c1[tt].y);
                a.us[6] = rb_f2bf(c1[tt].z); a.us[7] = rb_f2bf(c1[tt].w);
                int t = h2 * 2 + tt;
                acc[t][0] = MFMA_BF16(a.v, cb0.v, acc[t][0], 0, 0, 0);
                acc[t][1] = MFMA_BF16(a.v, cb1.v, acc[t][1], 0, 0, 0);
            }
        }
    }

    // f32 gather pipeline over the 26 non-center offsets (r2 shape)
    float4 fA0[4], fA1[4], fB0[4], fB1[4];
    GATHER4F(fA, jA);                  // kk=0
    GATHER4F(fB, jB);                  // kk=1

    int jE = okv ? __builtin_nontemporal_load(nbr + (size_t)KIDX(2) * NV + v64) : -1;
    int jO = okv ? __builtin_nontemporal_load(nbr + (size_t)KIDX(3) * NV + v64) : -1;

    #pragma unroll
    for (int p = 0; p < 13; ++p) {
        int jE2 = -1, jO2 = -1;
        if (2 * p + 4 < 26 && okv)
            jE2 = __builtin_nontemporal_load(nbr + (size_t)KIDX(2 * p + 4) * NV + v64);
        if (2 * p + 5 < 26 && okv)
            jO2 = __builtin_nontemporal_load(nbr + (size_t)KIDX(2 * p + 5) * NV + v64);

        CONSUMEF(2 * p, fA);
        if (2 * p + 2 < 26) GATHER4F(fA, jE);

        CONSUMEF(2 * p + 1, fB);
        if (2 * p + 3 < 26) GATHER4F(fB, jO);

        jE = jE2; jO = jO2;
    }

    // epilogue: LN + ReLU -> bf16 h. C/D: cout = lane&15 (+16), row = q*4+r.
    const float gv0 = gf[n],  gv1 = gf[n + 16];
    const float bv0 = bfv[n], bv1 = bfv[n + 16];
    #pragma unroll
    for (int t = 0; t < 4; ++t) {
        #pragma unroll
        for (int r = 0; r < 4; ++r) {
            float x0 = acc[t][0][r], x1 = acc[t][1][r];
            float s  = x0 + x1;
            float ss = x0 * x0 + x1 * x1;
            #pragma unroll
            for (int mm = 1; mm <= 8; mm <<= 1) {
                s  += __shfl_xor(s, mm);
                ss += __shfl_xor(ss, mm);
            }
            float mu  = s * (1.f / 32.f);
            float var = ss * (1.f / 32.f) - mu * mu;
            float rs  = rsqrtf(var + 1e-6f);
            int vv = i0 + t * 16 + q * 4 + r;
            if (vv < NV) {
                float y0 = (x0 - mu) * rs * gv0 + bv0;
                float y1 = (x1 - mu) * rs * gv1 + bv1;
                hbuf[(size_t)vv * 32 + n]      = rb_f2bf(fmaxf(y0, 0.f));
                hbuf[(size_t)vv * 32 + n + 16] = rb_f2bf(fmaxf(y1, 0.f));
            }
        }
    }
}

// =================  PASS 2: bf16 gathers from h (r2-proven)  =================
// out(f32) = relu(LN(conv2(h)) + x). Byte-identical structure to r2's 82us
// kernel: 26-offset LDS table, center B-frags in regs from global W2.

#define GATHER4(gbuf, jall)                                                   \
    do {                                                                      \
        _Pragma("unroll")                                                     \
        for (int _t = 0; _t < 4; ++_t) {                                      \
            int _j = __shfl((jall), _t * 16 + n);                             \
            gbuf[_t] = make_int4(0, 0, 0, 0);                                 \
            if (_j >= 0)                                                      \
                gbuf[_t] = *(const int4*)(gsrc + ((size_t)_j << 5) + qo);     \
        }                                                                     \
    } while (0)

#define CONSUME(kk, gbuf)                                                     \
    do {                                                                      \
        ABu _b0, _b1;                                                         \
        _b0.i4 = *(const int4*)(Bp + (kk) * 1024 + lane * 8);                 \
        _b1.i4 = *(const int4*)(Bp + (kk) * 1024 + 512 + lane * 8);           \
        _Pragma("unroll")                                                     \
        for (int _t = 0; _t < 4; ++_t) {                                      \
            ABu _a; _a.i4 = gbuf[_t];                                         \
            acc[_t][0] = MFMA_BF16(_a.v, _b0.v, acc[_t][0], 0, 0, 0);         \
            acc[_t][1] = MFMA_BF16(_a.v, _b1.v, acc[_t][1], 0, 0, 0);         \
        }                                                                     \
    } while (0)

#define NBLOAD(kk)                                                            \
    (okv ? __builtin_nontemporal_load(nbr + (size_t)KIDX(kk) * NV + v64) : -1)

__global__ __launch_bounds__(512, 4) void pass2_kernel(
    const float* __restrict__ xf,     // x [NV,32] f32 (residual)
    const int*   __restrict__ nbr,    // [27,NV]
    const float* __restrict__ Wf,     // W2 [27,32,32] f32
    const float* __restrict__ gf,     // [32]
    const float* __restrict__ bfv,    // [32]
    float*       __restrict__ outf,   // [NV,32] f32
    const unsigned short* __restrict__ gsrc)  // h [NV,32] bf16
{
    __shared__ __align__(16) unsigned short Bp[26 * 1024];
    for (int e = threadIdx.x; e < 26 * 1024; e += 512) {
        int kk = e >> 10;
        int k  = KIDX(kk);
        int r  = e & 1023;
        int f  = r >> 9;
        int ll = (r >> 3) & 63;
        int j  = r & 7;
        int ci = ((ll >> 4) << 3) + j;
        int co = (ll & 15) + (f << 4);
        Bp[e] = rb_f2bf(Wf[k * 1024 + ci * 32 + co]);
    }

    const int  lane = threadIdx.x & 63;
    const int  wv   = threadIdx.x >> 6;
    const int  q    = lane >> 4, n = lane & 15;
    const int  i0   = blockIdx.x * 512 + wv * 64;
    const int  v64  = i0 + lane;
    const bool okv  = v64 < NV;
    const int  qo   = q * 8;          // bf16-element offset within row

    // center-offset (k=13, identity map) B fragments in registers
    ABu cb0, cb1;
    #pragma unroll
    for (int j = 0; j < 8; ++j) {
        int ci = (q << 3) + j;
        cb0.us[j] = rb_f2bf(Wf[13 * 1024 + ci * 32 + n]);
        cb1.us[j] = rb_f2bf(Wf[13 * 1024 + ci * 32 + n + 16]);
    }
    __syncthreads();

    f32x4 acc[4][2];
    #pragma unroll
    for (int t = 0; t < 4; ++t) {
        acc[t][0] = (f32x4){0.f, 0.f, 0.f, 0.f};
        acc[t][1] = (f32x4){0.f, 0.f, 0.f, 0.f};
    }

    int jA = NBLOAD(0);
    int jB = NBLOAD(1);

    int4 cgb[4];
    #pragma unroll
    for (int t = 0; t < 4; ++t) {
        int vt = i0 + t * 16 + n;
        cgb[t] = make_int4(0, 0, 0, 0);
        if (vt < NV) cgb[t] = *(const int4*)(gsrc + ((size_t)vt << 5) + qo);
    }

    int4 gA[4], gB[4];
    GATHER4(gA, jA);
    GATHER4(gB, jB);

    int jE = NBLOAD(2);
    int jO = NBLOAD(3);

    #pragma unroll
    for (int t = 0; t < 4; ++t) {
        ABu a; a.i4 = cgb[t];
        acc[t][0] = MFMA_BF16(a.v, cb0.v, acc[t][0], 0, 0, 0);
        acc[t][1] = MFMA_BF16(a.v, cb1.v, acc[t][1], 0, 0, 0);
    }

    #pragma unroll
    for (int p = 0; p < 13; ++p) {
        int jE2 = -1, jO2 = -1;
        if (2 * p + 4 < 26) jE2 = NBLOAD(2 * p + 4);
        if (2 * p + 5 < 26) jO2 = NBLOAD(2 * p + 5);

        CONSUME(2 * p, gA);
        if (2 * p + 2 < 26) GATHER4(gA, jE);

        CONSUME(2 * p + 1, gB);
        if (2 * p + 3 < 26) GATHER4(gB, jO);

        jE = jE2; jO = jO2;
    }

    const float gv0 = gf[n],  gv1 = gf[n + 16];
    const float bv0 = bfv[n], bv1 = bfv[n + 16];
    #pragma unroll
    for (int t = 0; t < 4; ++t) {
        #pragma unroll
        for (int r = 0; r < 4; ++r) {
            float x0 = acc[t][0][r], x1 = acc[t][1][r];
            float s  = x0 + x1;
            float ss = x0 * x0 + x1 * x1;
            #pragma unroll
            for (int mm = 1; mm <= 8; mm <<= 1) {
                s  += __shfl_xor(s, mm);
                ss += __shfl_xor(ss, mm);
            }
            float mu  = s * (1.f / 32.f);
            float var = ss * (1.f / 32.f) - mu * mu;
            float rs  = rsqrtf(var + 1e-6f);
            int vv = i0 + t * 16 + q * 4 + r;
            if (vv < NV) {
                float y0 = (x0 - mu) * rs * gv0 + bv0 + xf[(size_t)vv * 32 + n];
                float y1 = (x1 - mu) * rs * gv1 + bv1 + xf[(size_t)vv * 32 + n + 16];
                outf[(size_t)vv * 32 + n]      = fmaxf(y0, 0.f);
                outf[(size_t)vv * 32 + n + 16] = fmaxf(y1, 0.f);
            }
        }
    }
}

extern "C" void kernel_launch(void* const* d_in, const int* in_sizes, int n_in,
                              void* d_out, int out_size, void* d_ws, size_t ws_size,
                              hipStream_t stream)
{
    // setup_inputs() dict order: x, nbr, W1, g1, b1, W2, g2, b2 — all f32 except nbr
    const float* x   = (const float*)d_in[0];
    const int*   nbr = (const int*)d_in[1];
    const float* W1  = (const float*)d_in[2];
    const float* g1  = (const float*)d_in[3];
    const float* b1  = (const float*)d_in[4];
    const float* W2  = (const float*)d_in[5];
    const float* g2  = (const float*)d_in[6];
    const float* b2  = (const float*)d_in[7];
    float* out = (float*)d_out;

    unsigned short* h = (unsigned short*)d_ws;   // 25.6 MB bf16 scratch (proven)

    // pass 1: h = relu(LN(conv1(x)))   -- f32 gathers, convert at consume
    pass1_kernel<<<NT, 512, 0, stream>>>(x, nbr, W1, g1, b1, h);
    // pass 2: out = relu(LN(conv2(h)) + x)  -- bf16 gathers (r2-proven)
    pass2_kernel<<<NT, 512, 0, stream>>>(x, nbr, W2, g2, b2, out, h);

    (void)in_sizes; (void)n_in; (void)out_size; (void)ws_size;
}

// Round 10
// 281.286 us; speedup vs baseline: 3.8954x; 1.1758x over previous
//
#include <hip/hip_runtime.h>
#include <hip/hip_bf16.h>

// Sparse 3^3 conv x2 + LayerNorm + ReLU + residual. N=400000, C=32, K=27.
// Contract: ALL float inputs are FLOAT32, output f32, nbr int32.
// Workspace: h (bf16, 25.6MB) at d_ws+0; xb (bf16 copy of x) at +25.6MB.
//
// Round-10 (post-mortem r9: f32-gather pass1 spilled -- VGPR pinned 64,
// WRITE 43.8 vs 25.6MB, 148us vs the 94 it replaced. AND the overhead
// accounting across r2/r3/r9 shows the ~100us gap between dur_us and
// sum(dispatch) is FIXED, not per-boundary -- removing dispatches buys
// nothing. So: back to r2's 3-dispatch structure, shorten the 82us passes.
// Theory: exposed latency = nbr index loads (HBM stream ~900cy, led by only
// ~500cy). Fix: deepen index prefetch 2->6 offsets in flight (rotating
// idx[6], 1 VGPR/offset; all indices static under the fully-unrolled pair
// loop). Data pipeline/center/epilogue byte-identical to r2's proven body.
// Pre-commit: passes >=78us with clean counters => index theory wrong =>
// next round = depth-2 DATA pipeline with the ~24 spare regs.)

#define NV 400000
#define NT 782          // ceil(NV / 512) blocks; 8 waves x 64 voxels each

typedef __bf16 bf16x8 __attribute__((ext_vector_type(8)));
typedef float  f32x4  __attribute__((ext_vector_type(4)));

union ABu { bf16x8 v; int4 i4; unsigned short us[8]; };

__device__ __forceinline__ unsigned short rb_f2bf(float f) {
    unsigned int u = __float_as_uint(f);
    return (unsigned short)((u + 0x7fffu + ((u >> 16) & 1u)) >> 16);
}

// k index for the 26 non-center offsets (skips k=13, the identity offset)
#define KIDX(kk) ((kk) + ((kk) >= 13 ? 1 : 0))

#define MFMA_BF16 __builtin_amdgcn_mfma_f32_16x16x32_bf16

// x (f32) -> bf16, 8 elems/thread. Exact grid: NV*32/8/512 = 3125 blocks.
__global__ __launch_bounds__(512) void xcvt_kernel(const float* __restrict__ xf,
                                                   unsigned short* __restrict__ xb)
{
    size_t i = ((size_t)blockIdx.x * 512 + threadIdx.x) * 8;
    float4 p0 = *(const float4*)(xf + i);
    float4 p1 = *(const float4*)(xf + i + 4);
    ABu a;
    a.us[0] = rb_f2bf(p0.x); a.us[1] = rb_f2bf(p0.y);
    a.us[2] = rb_f2bf(p0.z); a.us[3] = rb_f2bf(p0.w);
    a.us[4] = rb_f2bf(p1.x); a.us[5] = rb_f2bf(p1.y);
    a.us[6] = rb_f2bf(p1.z); a.us[7] = rb_f2bf(p1.w);
    *(int4*)(xb + i) = a.i4;
}

// Gather the 4 tile-slots for one offset from a wave-wide index register.
// jall lane l holds nbr index of voxel i0+l; tile t row n needs lane t*16+n.
#define GATHER4(gbuf, jall)                                                   \
    do {                                                                      \
        _Pragma("unroll")                                                     \
        for (int _t = 0; _t < 4; ++_t) {                                      \
            int _j = __shfl((jall), _t * 16 + n);                             \
            gbuf[_t] = make_int4(0, 0, 0, 0);                                 \
            if (_j >= 0)                                                      \
                gbuf[_t] = *(const int4*)(gsrc + ((size_t)_j << 5) + qo);     \
        }                                                                     \
    } while (0)

// Consume one offset's gather buffer: 2 LDS B-frag reads + 8 MFMAs.
#define CONSUME(kk, gbuf)                                                     \
    do {                                                                      \
        ABu _b0, _b1;                                                         \
        _b0.i4 = *(const int4*)(Bp + (kk) * 1024 + lane * 8);                 \
        _b1.i4 = *(const int4*)(Bp + (kk) * 1024 + 512 + lane * 8);           \
        _Pragma("unroll")                                                     \
        for (int _t = 0; _t < 4; ++_t) {                                      \
            ABu _a; _a.i4 = gbuf[_t];                                         \
            acc[_t][0] = MFMA_BF16(_a.v, _b0.v, acc[_t][0], 0, 0, 0);         \
            acc[_t][1] = MFMA_BF16(_a.v, _b1.v, acc[_t][1], 0, 0, 0);         \
        }                                                                     \
    } while (0)

#define NBLOAD(kk)                                                            \
    (okv ? __builtin_nontemporal_load(nbr + (size_t)KIDX(kk) * NV + v64) : -1)

// WRITE_OUT=false: h(bf16) = relu(LN(conv1(xb)))       gsrc = xb
// WRITE_OUT=true : out(f32) = relu(LN(conv2(h)) + x)   gsrc = h
template <bool WRITE_OUT>
__global__ __launch_bounds__(512, 4) void pass_kernel(
    const float* __restrict__ xf,     // x [NV,32] f32 (residual, pass 2)
    const int*   __restrict__ nbr,    // [27,NV]
    const float* __restrict__ Wf,     // [27,32,32] f32
    const float* __restrict__ gf,     // [32]
    const float* __restrict__ bfv,    // [32]
    float*       __restrict__ outf,   // [NV,32] f32
    unsigned short* __restrict__ hbuf,// [NV,32] bf16 (pass-1 dst)
    const unsigned short* __restrict__ gsrc)  // bf16 gather source
{
    // Bp[kk*1024 + f*512 + lane*8 + j] = W[k][ci=(lane>>4)*8+j][co=(lane&15)+16f]
    __shared__ __align__(16) unsigned short Bp[26 * 1024];

    const int  lane = threadIdx.x & 63;
    const int  wv   = threadIdx.x >> 6;
    const int  q    = lane >> 4, n = lane & 15;
    const int  i0   = blockIdx.x * 512 + wv * 64;
    const int  v64  = i0 + lane;
    const bool okv  = v64 < NV;
    const int  qo   = q * 8;          // bf16-element offset within row

    // ---- deep index prefetch: 6 offsets (3 pairs) in flight, issued FIRST
    // so the HBM latency (~900cy) hides under the LDS fill + prologue. ----
    int idx[6];
    #pragma unroll
    for (int kk = 0; kk < 6; ++kk) idx[kk] = NBLOAD(kk);

    // center self-rows (identity map k=13, coalesced) -- issued early too
    int4 cgb[4];
    #pragma unroll
    for (int t = 0; t < 4; ++t) {
        int vt = i0 + t * 16 + n;
        cgb[t] = make_int4(0, 0, 0, 0);
        if (vt < NV) cgb[t] = *(const int4*)(gsrc + ((size_t)vt << 5) + qo);
    }

    // center-offset B fragments from global f32 weights (independent of LDS)
    ABu cb0, cb1;
    #pragma unroll
    for (int j = 0; j < 8; ++j) {
        int ci = (q << 3) + j;
        cb0.us[j] = rb_f2bf(Wf[13 * 1024 + ci * 32 + n]);
        cb1.us[j] = rb_f2bf(Wf[13 * 1024 + ci * 32 + n + 16]);
    }

    // LDS fill: 26 non-center offsets (long; covers the loads above)
    for (int e = threadIdx.x; e < 26 * 1024; e += 512) {
        int kk = e >> 10;
        int k  = KIDX(kk);
        int r  = e & 1023;
        int f  = r >> 9;
        int ll = (r >> 3) & 63;
        int j  = r & 7;
        int ci = ((ll >> 4) << 3) + j;
        int co = (ll & 15) + (f << 4);
        Bp[e] = rb_f2bf(Wf[k * 1024 + ci * 32 + co]);
    }
    __syncthreads();

    f32x4 acc[4][2];
    #pragma unroll
    for (int t = 0; t < 4; ++t) {
        acc[t][0] = (f32x4){0.f, 0.f, 0.f, 0.f};
        acc[t][1] = (f32x4){0.f, 0.f, 0.f, 0.f};
    }

    // gathers for pair 0 issued first, then center MFMA covers their latency
    int4 gA[4], gB[4];
    GATHER4(gA, idx[0]);               // kk=0
    GATHER4(gB, idx[1]);               // kk=1

    #pragma unroll
    for (int t = 0; t < 4; ++t) {
        ABu a; a.i4 = cgb[t];
        acc[t][0] = MFMA_BF16(a.v, cb0.v, acc[t][0], 0, 0, 0);
        acc[t][1] = MFMA_BF16(a.v, cb1.v, acc[t][1], 0, 0, 0);
    }

    // ---- main pipeline: 13 pairs, fully unrolled; idx slots rotate mod 6
    // (all subscripts compile-time constant). Index lead = 2 full iterations
    // (~800-1000cy >= HBM latency); data lead = 1 consume (L2-hit scale).
    // Slot audit: iter p writes slots (2p)%6,(2p+1)%6 for pair p+3; gathers
    // read (2p+2)%6,(2p+3)%6 (pair p+1, loaded 2 iters ago) -- disjoint. ----
    #pragma unroll
    for (int p = 0; p < 13; ++p) {
        if (2 * p + 6 < 26) idx[(2 * p + 6) % 6] = NBLOAD(2 * p + 6);
        if (2 * p + 7 < 26) idx[(2 * p + 7) % 6] = NBLOAD(2 * p + 7);

        CONSUME(2 * p, gA);
        if (2 * p + 2 < 26) GATHER4(gA, idx[(2 * p + 2) % 6]);

        CONSUME(2 * p + 1, gB);
        if (2 * p + 3 < 26) GATHER4(gB, idx[(2 * p + 3) % 6]);
    }

    // epilogue. C/D layout: cout = lane&15 (+16 frag1), voxel row = q*4+r.
    const float gv0 = gf[n],  gv1 = gf[n + 16];
    const float bv0 = bfv[n], bv1 = bfv[n + 16];
    #pragma unroll
    for (int t = 0; t < 4; ++t) {
        #pragma unroll
        for (int r = 0; r < 4; ++r) {
            float x0 = acc[t][0][r], x1 = acc[t][1][r];
            float s  = x0 + x1;
            float ss = x0 * x0 + x1 * x1;
            #pragma unroll
            for (int mm = 1; mm <= 8; mm <<= 1) {   // LN reduce, 16-lane group
                s  += __shfl_xor(s, mm);
                ss += __shfl_xor(ss, mm);
            }
            float mu  = s * (1.f / 32.f);
            float var = ss * (1.f / 32.f) - mu * mu;
            float rs  = rsqrtf(var + 1e-6f);
            int vv = i0 + t * 16 + q * 4 + r;
            if (vv < NV) {
                float y0 = (x0 - mu) * rs * gv0 + bv0;
                float y1 = (x1 - mu) * rs * gv1 + bv1;
                if constexpr (WRITE_OUT) {
                    y0 += xf[(size_t)vv * 32 + n];
                    y1 += xf[(size_t)vv * 32 + n + 16];
                    outf[(size_t)vv * 32 + n]      = fmaxf(y0, 0.f);
                    outf[(size_t)vv * 32 + n + 16] = fmaxf(y1, 0.f);
                } else {
                    hbuf[(size_t)vv * 32 + n]      = rb_f2bf(fmaxf(y0, 0.f));
                    hbuf[(size_t)vv * 32 + n + 16] = rb_f2bf(fmaxf(y1, 0.f));
                }
            }
        }
    }
}

// Fallback pass-1 for tiny workspace (no xb room): f32 gathers from x,
// round-0-proven serial structure. Only used when ws_size < 51.2MB.
__global__ __launch_bounds__(512, 4) void pass1_f32_kernel(
    const float* __restrict__ xf, const int* __restrict__ nbr,
    const float* __restrict__ Wf, const float* __restrict__ gf,
    const float* __restrict__ bfv, unsigned short* __restrict__ hbuf)
{
    __shared__ __align__(16) unsigned short Bp[27 * 1024];
    for (int e = threadIdx.x; e < 27 * 1024; e += 512) {
        int k = e >> 10, r = e & 1023, f = r >> 9;
        int ll = (r >> 3) & 63, j = r & 7;
        int ci = ((ll >> 4) << 3) + j, co = (ll & 15) + (f << 4);
        Bp[e] = rb_f2bf(Wf[k * 1024 + ci * 32 + co]);
    }
    __syncthreads();
    const int lane = threadIdx.x & 63, wv = threadIdx.x >> 6;
    const int q = lane >> 4, n = lane & 15;
    const int i0 = blockIdx.x * 512 + wv * 64;
    f32x4 acc[4][2];
    #pragma unroll
    for (int t = 0; t < 4; ++t) { acc[t][0] = (f32x4){0,0,0,0}; acc[t][1] = (f32x4){0,0,0,0}; }
    for (int k = 0; k < 27; ++k) {
        ABu b0, b1;
        b0.i4 = *(const int4*)(Bp + k * 1024 + lane * 8);
        b1.i4 = *(const int4*)(Bp + k * 1024 + 512 + lane * 8);
        const int* nb = nbr + (size_t)k * NV;
        #pragma unroll
        for (int t = 0; t < 4; ++t) {
            int v = i0 + t * 16 + n;
            int jn = (v < NV) ? nb[v] : -1;
            if (__ballot(jn >= 0) == 0ull) continue;
            ABu a; a.i4 = make_int4(0, 0, 0, 0);
            if (jn >= 0) {
                const float* src = xf + (size_t)jn * 32 + q * 8;
                float4 p0 = *(const float4*)(src);
                float4 p1 = *(const float4*)(src + 4);
                a.us[0] = rb_f2bf(p0.x); a.us[1] = rb_f2bf(p0.y);
                a.us[2] = rb_f2bf(p0.z); a.us[3] = rb_f2bf(p0.w);
                a.us[4] = rb_f2bf(p1.x); a.us[5] = rb_f2bf(p1.y);
                a.us[6] = rb_f2bf(p1.z); a.us[7] = rb_f2bf(p1.w);
            }
            acc[t][0] = MFMA_BF16(a.v, b0.v, acc[t][0], 0, 0, 0);
            acc[t][1] = MFMA_BF16(a.v, b1.v, acc[t][1], 0, 0, 0);
        }
    }
    const float gv0 = gf[n], gv1 = gf[n + 16];
    const float bv0 = bfv[n], bv1 = bfv[n + 16];
    #pragma unroll
    for (int t = 0; t < 4; ++t) {
        #pragma unroll
        for (int r = 0; r < 4; ++r) {
            float x0 = acc[t][0][r], x1 = acc[t][1][r];
            float s = x0 + x1, ss = x0 * x0 + x1 * x1;
            #pragma unroll
            for (int mm = 1; mm <= 8; mm <<= 1) { s += __shfl_xor(s, mm); ss += __shfl_xor(ss, mm); }
            float mu = s * (1.f / 32.f);
            float var = ss * (1.f / 32.f) - mu * mu;
            float rs = rsqrtf(var + 1e-6f);
            int vv = i0 + t * 16 + q * 4 + r;
            if (vv < NV) {
                float y0 = (x0 - mu) * rs * gv0 + bv0;
                float y1 = (x1 - mu) * rs * gv1 + bv1;
                hbuf[(size_t)vv * 32 + n]      = rb_f2bf(fmaxf(y0, 0.f));
                hbuf[(size_t)vv * 32 + n + 16] = rb_f2bf(fmaxf(y1, 0.f));
            }
        }
    }
}

extern "C" void kernel_launch(void* const* d_in, const int* in_sizes, int n_in,
                              void* d_out, int out_size, void* d_ws, size_t ws_size,
                              hipStream_t stream)
{
    // setup_inputs() dict order: x, nbr, W1, g1, b1, W2, g2, b2 — all f32 except nbr
    const float* x   = (const float*)d_in[0];
    const int*   nbr = (const int*)d_in[1];
    const float* W1  = (const float*)d_in[2];
    const float* g1  = (const float*)d_in[3];
    const float* b1  = (const float*)d_in[4];
    const float* W2  = (const float*)d_in[5];
    const float* g2  = (const float*)d_in[6];
    const float* b2  = (const float*)d_in[7];
    float* out = (float*)d_out;

    unsigned short* h  = (unsigned short*)d_ws;              // 25.6 MB
    unsigned short* xb = h + (size_t)NV * 32;                // +25.6 MB
    const bool have_xb = ws_size >= (size_t)NV * 32 * 2 * 2; // 51.2 MB needed

    if (have_xb) {
        // pass 0: xb = bf16(x)
        xcvt_kernel<<<3125, 512, 0, stream>>>(x, xb);
        // pass 1: h = relu(LN(conv1(xb)))
        pass_kernel<false><<<NT, 512, 0, stream>>>(x, nbr, W1, g1, b1, out, h, xb);
    } else {
        pass1_f32_kernel<<<NT, 512, 0, stream>>>(x, nbr, W1, g1, b1, h);
    }
    // pass 2: out = relu(LN(conv2(h)) + x)
    pass_kernel<true><<<NT, 512, 0, stream>>>(x, nbr, W2, g2, b2, out, h, h);

    (void)in_sizes; (void)n_in; (void)out_size;
}